// Round 1
// baseline (447.019 us; speedup 1.0000x reference)
//
#include <hip/hip_runtime.h>
#include <stdint.h>

// ---------- types ----------
typedef __attribute__((ext_vector_type(8))) short   short8;
typedef __attribute__((ext_vector_type(8))) __bf16  bf16x8;
typedef __attribute__((ext_vector_type(4))) float   floatx4;

#define DEV static __device__ __forceinline__

// f32 -> bf16 (RNE) raw bits
DEV unsigned short f2b(float f) {
  union { float f; unsigned u; } v; v.f = f;
  unsigned u = v.u;
  unsigned r = u + 0x7FFFu + ((u >> 16) & 1u);
  return (unsigned short)(r >> 16);
}

// async global->LDS, 16 bytes per lane. LDS dest must be wave-uniform base + lane*16.
DEV void gload_lds16(const void* g, void* l) {
  __builtin_amdgcn_global_load_lds(
      (const __attribute__((address_space(1))) unsigned int*)g,
      (__attribute__((address_space(3))) unsigned int*)l,
      16, 0, 0);
}

// ---------- weights f32->bf16 convert + sums zero-init ----------
__global__ void cvtw_kernel(const float* __restrict__ a, unsigned short* __restrict__ oa, int na4,
                            const float* __restrict__ b, unsigned short* __restrict__ ob, int nb4,
                            float* __restrict__ zp, int nz) {
  int i = blockIdx.x * blockDim.x + threadIdx.x;
  if (i < na4) {
    float4 v = ((const float4*)a)[i];
    ushort4 o; o.x = f2b(v.x); o.y = f2b(v.y); o.z = f2b(v.z); o.w = f2b(v.w);
    ((ushort4*)oa)[i] = o;
  } else if (i < na4 + nb4) {
    int k = i - na4;
    float4 v = ((const float4*)b)[k];
    ushort4 o; o.x = f2b(v.x); o.y = f2b(v.y); o.z = f2b(v.z); o.w = f2b(v.w);
    ((ushort4*)ob)[k] = o;
  } else if (i < na4 + nb4 + nz) {
    zp[i - na4 - nb4] = 0.f;
  }
}

// ---------- projection GEMM: C[M][256] = A[M][K] * Bt[256][K]^T ----------
// 64 m x 256 n per block (full N => A fetched exactly once), 512 threads (8 waves,
// 2m x 4n split) -> 16 waves/CU at 2 blocks/CU.
// Software-pipelined: Bs double-buffered via global_load_lds; A f32 prefetched
// into registers. Both prefetches issue AFTER the second barrier so they overlap
// the frag-read/MFMA/HT phase and drain at the NEXT iteration's barrier.
// WRITE_HT: also emit the staged A tile transposed to HT [16][K][2048] bf16.
// At2 [32 k][66 l]: write bank = (4*seg + 33*j + row/2) mod 32 -> 32 banks x 2-way (free).
template <int WRITE_HT>
__global__ __launch_bounds__(512) void proj_gemm(
    const float* __restrict__ A32, const unsigned short* __restrict__ Bt,
    unsigned short* __restrict__ C, unsigned short* __restrict__ HT,
    int K, int lda) {
  __shared__ unsigned short As[64 * 32];         // 4 KB
  __shared__ unsigned short Bs[2][256 * 32];     // 32 KB (double-buffered)
  __shared__ unsigned short At2[WRITE_HT ? 32 * 66 : 1];  // 4.2 KB

  const int m0   = blockIdx.x * 64;
  const int t    = threadIdx.x;
  const int lane = t & 63;
  const int wave = t >> 6;            // 0..7
  const int wm   = (wave & 1) * 32;
  const int wn   = (wave >> 1) * 64;
  const int r16  = lane & 15;
  const int q    = lane >> 4;

  // A staging: thread -> (row 0..63, seg 0..7), one float4 (4 k-elems) each
  const int arow = t >> 3;
  const int aseg = t & 7;
  const float* ag = A32 + (size_t)(m0 + arow) * lda + aseg * 4;

  floatx4 acc[2][4];
#pragma unroll
  for (int i = 0; i < 2; ++i)
#pragma unroll
    for (int j = 0; j < 4; ++j) acc[i][j] = (floatx4){0.f, 0.f, 0.f, 0.f};

  // prologue: B(0) -> Bs[0] (async), A(0) -> regs
#pragma unroll
  for (int cc = 0; cc < 2; ++cc) {
    int c = t + cc * 512;
    gload_lds16(Bt + (size_t)(c >> 2) * K + (c & 3) * 8, &Bs[0][c * 8]);
  }
  float4 v = *(const float4*)ag;

  for (int kt = 0; kt < K; kt += 32) {
    const int cur = (kt >> 5) & 1;
    __syncthreads();  // drains vmcnt: B(kt) is in Bs[cur], v is ready; prev LDS reads done

    // phase 2 (cheap): LDS writes only
    ushort4 pv;
    pv.x = f2b(v.x); pv.y = f2b(v.y); pv.z = f2b(v.z); pv.w = f2b(v.w);
    *(ushort4*)&As[t * 4] = pv;
    if constexpr (WRITE_HT) {
      At2[(aseg * 4 + 0) * 66 + arow] = pv.x;
      At2[(aseg * 4 + 1) * 66 + arow] = pv.y;
      At2[(aseg * 4 + 2) * 66 + arow] = pv.z;
      At2[(aseg * 4 + 3) * 66 + arow] = pv.w;
    }
    __syncthreads();  // As/At2 visible

    // phase 3: issue next-tile prefetches first (overlap with MFMA below),
    // they drain at the next iteration's barrier.
    if (kt + 32 < K) {
#pragma unroll
      for (int cc = 0; cc < 2; ++cc) {
        int c = t + cc * 512;
        gload_lds16(Bt + (size_t)(c >> 2) * K + (kt + 32) + (c & 3) * 8,
                    &Bs[cur ^ 1][c * 8]);
      }
      v = *(const float4*)(ag + kt + 32);
    }

    bf16x8 af[2], bfr[4];
#pragma unroll
    for (int i = 0; i < 2; ++i) af[i]  = *(const bf16x8*)&As[(wm + i * 16 + r16) * 32 + q * 8];
#pragma unroll
    for (int j = 0; j < 4; ++j) bfr[j] = *(const bf16x8*)&Bs[cur][(wn + j * 16 + r16) * 32 + q * 8];
#pragma unroll
    for (int i = 0; i < 2; ++i)
#pragma unroll
      for (int j = 0; j < 4; ++j)
        acc[i][j] = __builtin_amdgcn_mfma_f32_16x16x32_bf16(af[i], bfr[j], acc[i][j], 0, 0, 0);

    if constexpr (WRITE_HT) {
      // readback: thread (d = t>>4, lc = t&15) reads At2[d][lc*4 .. +4]
      // as 2x b32 (word = d*33 + lc*2; banks d+2lc mod 32 -> 2-way, free),
      // stores 8 B to HT (16 lanes -> 128 B contiguous per k-row).
      const int d  = t >> 4;
      const int lc = t & 15;
      const unsigned* w = (const unsigned*)At2 + d * 33 + lc * 2;
      union { unsigned u[2]; ushort4 s; } vv;
      vv.u[0] = w[0]; vv.u[1] = w[1];
      const int b  = m0 >> 11;        // 2048 rows per batch
      const int l0 = m0 & 2047;
      *(ushort4*)&HT[((size_t)b * 1280 + kt + d) * 2048 + l0 + lc * 4] = vv.s;
    }
  }

  // epilogue: bf16 store, ldc = 256
#pragma unroll
  for (int i = 0; i < 2; ++i) {
#pragma unroll
    for (int r = 0; r < 4; ++r) {
      int m = m0 + wm + i * 16 + q * 4 + r;
#pragma unroll
      for (int j = 0; j < 4; ++j) {
        int n = wn + j * 16 + r16;
        C[(size_t)m * 256 + n] = f2b(acc[i][j][r]);
      }
    }
  }
}

// ---------- NT GEMM, 128x128 tile, XCD-swizzled 1D grid ----------
// Block decode: xcd = g&7 owns batches {xcd*2, xcd*2+1} (B=16, 8 XCDs).
// EPI 1: C=bf16 exp(v*escale), atomicAdd row sums.  EPI 2: C=f32 v/sums[row].
template <int EPI>
__global__ void gemm_nt(const unsigned short* __restrict__ Ab, const unsigned short* __restrict__ Btb,
                        void* __restrict__ Cpv, float* __restrict__ sums,
                        int K, int lda, int ldb, int ldc,
                        long long sA, long long sB, long long sC, int sstride,
                        float escale, int nx, int tiles_pb) {
  __shared__ unsigned short As[128 * 32];
  __shared__ unsigned short Bs[128 * 32];

  const int g   = blockIdx.x;
  const int xcd = g & 7;
  const int jj  = g >> 3;
  const int bz  = xcd * 2 + jj / tiles_pb;
  const int tt  = jj % tiles_pb;
  const int m0  = (tt / nx) * 128;
  const int n0  = (tt % nx) * 128;

  const int t    = threadIdx.x;
  const int lane = t & 63;
  const int wave = t >> 6;
  const int wm   = (wave & 1) * 64;
  const int wn   = (wave >> 1) * 64;
  const int r16  = lane & 15;
  const int q    = lane >> 4;

  const unsigned short* Bt = Btb + (long long)bz * sB;
  const unsigned short* A  = Ab + (long long)bz * sA;

  floatx4 acc[4][4];
#pragma unroll
  for (int i = 0; i < 4; ++i)
#pragma unroll
    for (int j = 0; j < 4; ++j) acc[i][j] = (floatx4){0.f, 0.f, 0.f, 0.f};

  for (int kt = 0; kt < K; kt += 32) {
    __syncthreads();
#pragma unroll
    for (int cc = 0; cc < 2; ++cc) {
      int c = t + cc * 256;
      gload_lds16(Bt + (size_t)(n0 + (c >> 2)) * ldb + kt + (c & 3) * 8, &Bs[c * 8]);
    }
#pragma unroll
    for (int cc = 0; cc < 2; ++cc) {
      int c = t + cc * 256;
      gload_lds16(A + (size_t)(m0 + (c >> 2)) * lda + kt + (c & 3) * 8, &As[c * 8]);
    }
    __syncthreads();

    bf16x8 af[4], bfr[4];
#pragma unroll
    for (int i = 0; i < 4; ++i) af[i]  = *(const bf16x8*)&As[(wm + i * 16 + r16) * 32 + q * 8];
#pragma unroll
    for (int j = 0; j < 4; ++j) bfr[j] = *(const bf16x8*)&Bs[(wn + j * 16 + r16) * 32 + q * 8];
#pragma unroll
    for (int i = 0; i < 4; ++i)
#pragma unroll
      for (int j = 0; j < 4; ++j)
        acc[i][j] = __builtin_amdgcn_mfma_f32_16x16x32_bf16(af[i], bfr[j], acc[i][j], 0, 0, 0);
  }

  if constexpr (EPI == 1) {
    unsigned short* C = (unsigned short*)Cpv + (long long)bz * sC;
#pragma unroll
    for (int i = 0; i < 4; ++i) {
#pragma unroll
      for (int r = 0; r < 4; ++r) {
        int m = m0 + wm + i * 16 + q * 4 + r;
        float ps = 0.f;
#pragma unroll
        for (int j = 0; j < 4; ++j) {
          int n = n0 + wn + j * 16 + r16;
          float v = __expf(acc[i][j][r] * escale);
          ps += v;
          C[(size_t)m * ldc + n] = f2b(v);
        }
        // reduce over the 16 lanes sharing this row
#pragma unroll
        for (int msk = 1; msk < 16; msk <<= 1) ps += __shfl_xor(ps, msk, 64);
        if (r16 == 0) atomicAdd(&sums[(long long)bz * sstride + m], ps);
      }
    }
  } else {
    float* C = (float*)Cpv + (long long)bz * sC;
    const float* sb = sums + (long long)bz * sstride;
#pragma unroll
    for (int i = 0; i < 4; ++i) {
#pragma unroll
      for (int r = 0; r < 4; ++r) {
        int m = m0 + wm + i * 16 + q * 4 + r;
        float sc = 1.0f / sb[m];
#pragma unroll
        for (int j = 0; j < 4; ++j) {
          int n = n0 + wn + j * 16 + r16;
          C[(size_t)m * ldc + n] = acc[i][j][r] * sc;
        }
      }
    }
  }
}

// ---------- launch ----------
extern "C" void kernel_launch(void* const* d_in, const int* in_sizes, int n_in,
                              void* d_out, int out_size, void* d_ws, size_t ws_size,
                              hipStream_t stream) {
  (void)in_sizes; (void)n_in; (void)out_size; (void)ws_size;
  const float* H  = (const float*)d_in[0];   // [16][2048][1280]
  const float* G  = (const float*)d_in[1];   // [16][512][768]
  const float* Wq = (const float*)d_in[2];   // [256][768]
  const float* Wk = (const float*)d_in[3];   // [256][1280]
  float* Z = (float*)d_out;                  // [16][512][1280]

  constexpr int B = 16, L = 2048, Dh = 1280, T = 512, Dg = 768, P = 256;

  char* ws = (char*)d_ws;
  size_t off = 0;
  auto alloc = [&](size_t bytes) { void* p = ws + off; off += (bytes + 255) & ~(size_t)255; return p; };
  unsigned short* Wqbf = (unsigned short*)alloc((size_t)P * Dg * 2);
  unsigned short* Wkbf = (unsigned short*)alloc((size_t)P * Dh * 2);
  unsigned short* Qbf  = (unsigned short*)alloc((size_t)B * T * P * 2);    // 4 MB
  unsigned short* Kbf  = (unsigned short*)alloc((size_t)B * L * P * 2);    // 16 MB
  unsigned short* HT   = (unsigned short*)alloc((size_t)B * Dh * L * 2);   // 80 MB
  unsigned short* E    = (unsigned short*)alloc((size_t)B * T * L * 2);    // 32 MB
  float*          sums = (float*)alloc((size_t)B * T * 4);
  // total ~132 MB of ws

  // weights convert + sums zero-init (one small kernel)
  {
    int na4 = P * Dg / 4, nb4 = P * Dh / 4, nz = B * T;
    cvtw_kernel<<<(na4 + nb4 + nz + 255) / 256, 256, 0, stream>>>(
        Wq, Wqbf, na4, Wk, Wkbf, nb4, sums, nz);
  }

  // Q = G(f32) * Wqbf^T : [8192][256], G fetched once
  proj_gemm<0><<<B * T / 64, 512, 0, stream>>>(G, Wqbf, Qbf, nullptr, Dg, Dg);
  // K = H(f32) * Wkbf^T : [32768][256], H fetched once; also emits HT bf16
  proj_gemm<1><<<B * L / 64, 512, 0, stream>>>(H, Wkbf, Kbf, HT, Dh, Dh);

  // E = exp(scale * Qb * Kb^T) + row sums : per b [512][2048], 64 tiles/batch
  gemm_nt<1><<<B * (T / 128) * (L / 128), 256, 0, stream>>>(
      Qbf, Kbf, E, sums, P, P, P, L,
      (long long)T * P, (long long)L * P, (long long)T * L, T,
      0.0625f, L / 128, (T / 128) * (L / 128));

  // Z = diag(1/sums) * Eb * HTb^T : per b [512][1280] f32, 40 tiles/batch
  gemm_nt<2><<<B * (T / 128) * (Dh / 128), 256, 0, stream>>>(
      E, HT, Z, sums, L, L, L, Dh,
      (long long)T * L, (long long)Dh * L, (long long)T * Dh, T,
      0.f, Dh / 128, (T / 128) * (Dh / 128));
}

// Round 2
// 410.854 us; speedup vs baseline: 1.0880x; 1.0880x over previous
//
#include <hip/hip_runtime.h>
#include <stdint.h>

// ---------- types ----------
typedef __attribute__((ext_vector_type(8))) short   short8;
typedef __attribute__((ext_vector_type(8))) __bf16  bf16x8;
typedef __attribute__((ext_vector_type(4))) float   floatx4;

#define DEV static __device__ __forceinline__

// f32 -> bf16 (RNE) raw bits
DEV unsigned short f2b(float f) {
  union { float f; unsigned u; } v; v.f = f;
  unsigned u = v.u;
  unsigned r = u + 0x7FFFu + ((u >> 16) & 1u);
  return (unsigned short)(r >> 16);
}

// async global->LDS, 16 bytes per lane. LDS dest must be wave-uniform base + lane*16.
DEV void gload_lds16(const void* g, void* l) {
  __builtin_amdgcn_global_load_lds(
      (const __attribute__((address_space(1))) unsigned int*)g,
      (__attribute__((address_space(3))) unsigned int*)l,
      16, 0, 0);
}

// ---------- weights f32->bf16 convert + sums zero-init ----------
__global__ void cvtw_kernel(const float* __restrict__ a, unsigned short* __restrict__ oa, int na4,
                            const float* __restrict__ b, unsigned short* __restrict__ ob, int nb4,
                            float* __restrict__ zp, int nz) {
  int i = blockIdx.x * blockDim.x + threadIdx.x;
  if (i < na4) {
    float4 v = ((const float4*)a)[i];
    ushort4 o; o.x = f2b(v.x); o.y = f2b(v.y); o.z = f2b(v.z); o.w = f2b(v.w);
    ((ushort4*)oa)[i] = o;
  } else if (i < na4 + nb4) {
    int k = i - na4;
    float4 v = ((const float4*)b)[k];
    ushort4 o; o.x = f2b(v.x); o.y = f2b(v.y); o.z = f2b(v.z); o.w = f2b(v.w);
    ((ushort4*)ob)[k] = o;
  } else if (i < na4 + nb4 + nz) {
    zp[i - na4 - nb4] = 0.f;
  }
}

// ---------- projection GEMM: C[M][256] = A[M][K] * Bt[256][K]^T ----------
// 64 m x 256 n per block, 256 threads (4 waves, round-0 geometry: 16 MFMAs/wave/K-step).
// Counted-vmcnt software pipeline (T3+T4): ALL staging is global_load_lds
// (A raw f32 -> Af32[2], B bf16 -> Bs[2]); raw s_barrier + s_waitcnt vmcnt(6)
// so stage(kt+1)/stage(kt+2) (6 vmem ops each) stay in flight across barriers.
// Per-iter cadence:
//   vmcnt(6)  [stage(kt) landed; stage(kt+1) stays in flight]
//   convert: Af32[cur] -> As bf16 (+At2 transposed)   (LDS only)
//   lgkmcnt(0); s_barrier                             [barrier A]
//   frag reads (As, Bs[cur]) + At2 readback
//   lgkmcnt(0); s_barrier                             [barrier B: buffers free]
//   issue stage(kt+2) -> buf[cur]; 16 MFMA; HT store
// Wait-count audit (6 ops/stage, 1 HT store/iter): newer-than-stage(kt) at the
// wait point is 6 (it=0), 7 (it=1), 8 (steady), so vmcnt(6) is always safe;
// last iteration uses vmcnt(0) (only stores newer).
// At2 write bank = (4*kc + jj + row/2) mod 32 -> conflict-free per step.
template <int WRITE_HT>
__global__ __launch_bounds__(256) void proj_gemm(
    const float* __restrict__ A32, const unsigned short* __restrict__ Bt,
    unsigned short* __restrict__ C, unsigned short* __restrict__ HT,
    int K, int lda) {
  __shared__ float          Af32[2][64 * 32];              // 16 KB (dbuf, raw f32 A)
  __shared__ unsigned short Bs[2][256 * 32];               // 32 KB (dbuf)
  __shared__ unsigned short As[64 * 32];                   // 4 KB  (bf16 A)
  __shared__ unsigned short At2[WRITE_HT ? 32 * 66 : 1];   // 4.2 KB (transposed)

  const int m0   = blockIdx.x * 64;
  const int t    = threadIdx.x;
  const int lane = t & 63;
  const int wave = t >> 6;            // 0..3
  const int wn   = wave * 64;
  const int r16  = lane & 15;
  const int q    = lane >> 4;
  const int nt   = K >> 5;

  floatx4 acc[4][4];
#pragma unroll
  for (int i = 0; i < 4; ++i)
#pragma unroll
    for (int j = 0; j < 4; ++j) acc[i][j] = (floatx4){0.f, 0.f, 0.f, 0.f};

  // stage(it) -> buf: A (2 chunks) then B (4 chunks); 6 vmem ops, program order.
  auto stage = [&](int it, int buf) {
    const int kt = it << 5;
#pragma unroll
    for (int cc = 0; cc < 2; ++cc) {
      int c = t + cc * 256;  // chunk 0..511: row = c>>3, kchunk = c&7 (4 f32 each)
      gload_lds16(A32 + (size_t)(m0 + (c >> 3)) * lda + kt + (c & 7) * 4,
                  &Af32[buf][c * 4]);
    }
#pragma unroll
    for (int cc = 0; cc < 4; ++cc) {
      int c = t + cc * 256;  // chunk 0..1023: nrow = c>>2, kseg = c&3 (8 bf16 each)
      gload_lds16(Bt + (size_t)(c >> 2) * K + kt + (c & 3) * 8, &Bs[buf][c * 8]);
    }
  };

  // prologue: 2-deep
  stage(0, 0);
  stage(1, 1);

  for (int it = 0; it < nt; ++it) {
    const int cur = it & 1;
    const int kt  = it << 5;

    if (it == nt - 1) { asm volatile("s_waitcnt vmcnt(0)" ::: "memory"); }
    else              { asm volatile("s_waitcnt vmcnt(6)" ::: "memory"); }
    __builtin_amdgcn_sched_barrier(0);

    // ---- convert phase (LDS->LDS): Af32[cur] -> As bf16 (+ At2 transposed) ----
    {
      const int row = t >> 3;   // 0..31 (chunk0) / +32 (chunk1)
      const int kc  = t & 7;    // k-chunk: 4 consecutive k
      float4 v0 = *(const float4*)&Af32[cur][t * 4];
      float4 v1 = *(const float4*)&Af32[cur][t * 4 + 1024];
      unsigned short e0[4], e1[4];
      e0[0] = f2b(v0.x); e0[1] = f2b(v0.y); e0[2] = f2b(v0.z); e0[3] = f2b(v0.w);
      e1[0] = f2b(v1.x); e1[1] = f2b(v1.y); e1[2] = f2b(v1.z); e1[3] = f2b(v1.w);
      ushort4 p0, p1;
      p0.x = e0[0]; p0.y = e0[1]; p0.z = e0[2]; p0.w = e0[3];
      p1.x = e1[0]; p1.y = e1[1]; p1.z = e1[2]; p1.w = e1[3];
      *(ushort4*)&As[row * 32 + kc * 4]        = p0;
      *(ushort4*)&As[(row + 32) * 32 + kc * 4] = p1;
      if constexpr (WRITE_HT) {
#pragma unroll
        for (int jj = 0; jj < 4; ++jj) {
          At2[(kc * 4 + jj) * 66 + row]      = e0[jj];
          At2[(kc * 4 + jj) * 66 + row + 32] = e1[jj];
        }
      }
    }
    asm volatile("s_waitcnt lgkmcnt(0)\n\ts_barrier" ::: "memory");  // barrier A
    __builtin_amdgcn_sched_barrier(0);

    // ---- frag phase: LDS reads only ----
    bf16x8 af[4], bfr[4];
#pragma unroll
    for (int i = 0; i < 4; ++i) af[i]  = *(const bf16x8*)&As[(i * 16 + r16) * 32 + q * 8];
#pragma unroll
    for (int j = 0; j < 4; ++j) bfr[j] = *(const bf16x8*)&Bs[cur][(wn + j * 16 + r16) * 32 + q * 8];
    union { unsigned u[4]; short8 s; } vv;
    if constexpr (WRITE_HT) {
      const int d  = t >> 3;   // k row 0..31
      const int lc = t & 7;
      const unsigned* w = (const unsigned*)At2 + d * 33 + lc * 4;
      vv.u[0] = w[0]; vv.u[1] = w[1]; vv.u[2] = w[2]; vv.u[3] = w[3];
    }
    asm volatile("s_waitcnt lgkmcnt(0)\n\ts_barrier" ::: "memory");  // barrier B
    __builtin_amdgcn_sched_barrier(0);

    // ---- post phase: prefetch 2 ahead, then compute/store ----
    if (it + 2 < nt) stage(it + 2, cur);

#pragma unroll
    for (int i = 0; i < 4; ++i)
#pragma unroll
      for (int j = 0; j < 4; ++j)
        acc[i][j] = __builtin_amdgcn_mfma_f32_16x16x32_bf16(af[i], bfr[j], acc[i][j], 0, 0, 0);

    if constexpr (WRITE_HT) {
      const int d  = t >> 3;
      const int lc = t & 7;
      const int b  = m0 >> 11;        // 2048 rows per batch
      const int l0 = m0 & 2047;
      *(short8*)&HT[((size_t)b * 1280 + kt + d) * 2048 + l0 + lc * 8] = vv.s;
    }
  }

  // epilogue: bf16 store, ldc = 256
#pragma unroll
  for (int i = 0; i < 4; ++i) {
#pragma unroll
    for (int r = 0; r < 4; ++r) {
      int m = m0 + i * 16 + q * 4 + r;
#pragma unroll
      for (int j = 0; j < 4; ++j) {
        int n = wn + j * 16 + r16;
        C[(size_t)m * 256 + n] = f2b(acc[i][j][r]);
      }
    }
  }
}

// ---------- NT GEMM, 128x128 tile, XCD-swizzled 1D grid ----------
// Block decode: xcd = g&7 owns batches {xcd*2, xcd*2+1} (B=16, 8 XCDs).
// EPI 1: C=bf16 exp(v*escale), atomicAdd row sums.  EPI 2: C=f32 v/sums[row].
template <int EPI>
__global__ void gemm_nt(const unsigned short* __restrict__ Ab, const unsigned short* __restrict__ Btb,
                        void* __restrict__ Cpv, float* __restrict__ sums,
                        int K, int lda, int ldb, int ldc,
                        long long sA, long long sB, long long sC, int sstride,
                        float escale, int nx, int tiles_pb) {
  __shared__ unsigned short As[128 * 32];
  __shared__ unsigned short Bs[128 * 32];

  const int g   = blockIdx.x;
  const int xcd = g & 7;
  const int jj  = g >> 3;
  const int bz  = xcd * 2 + jj / tiles_pb;
  const int tt  = jj % tiles_pb;
  const int m0  = (tt / nx) * 128;
  const int n0  = (tt % nx) * 128;

  const int t    = threadIdx.x;
  const int lane = t & 63;
  const int wave = t >> 6;
  const int wm   = (wave & 1) * 64;
  const int wn   = (wave >> 1) * 64;
  const int r16  = lane & 15;
  const int q    = lane >> 4;

  const unsigned short* Bt = Btb + (long long)bz * sB;
  const unsigned short* A  = Ab + (long long)bz * sA;

  floatx4 acc[4][4];
#pragma unroll
  for (int i = 0; i < 4; ++i)
#pragma unroll
    for (int j = 0; j < 4; ++j) acc[i][j] = (floatx4){0.f, 0.f, 0.f, 0.f};

  for (int kt = 0; kt < K; kt += 32) {
    __syncthreads();
#pragma unroll
    for (int cc = 0; cc < 2; ++cc) {
      int c = t + cc * 256;
      gload_lds16(Bt + (size_t)(n0 + (c >> 2)) * ldb + kt + (c & 3) * 8, &Bs[c * 8]);
    }
#pragma unroll
    for (int cc = 0; cc < 2; ++cc) {
      int c = t + cc * 256;
      gload_lds16(A + (size_t)(m0 + (c >> 2)) * lda + kt + (c & 3) * 8, &As[c * 8]);
    }
    __syncthreads();

    bf16x8 af[4], bfr[4];
#pragma unroll
    for (int i = 0; i < 4; ++i) af[i]  = *(const bf16x8*)&As[(wm + i * 16 + r16) * 32 + q * 8];
#pragma unroll
    for (int j = 0; j < 4; ++j) bfr[j] = *(const bf16x8*)&Bs[(wn + j * 16 + r16) * 32 + q * 8];
#pragma unroll
    for (int i = 0; i < 4; ++i)
#pragma unroll
      for (int j = 0; j < 4; ++j)
        acc[i][j] = __builtin_amdgcn_mfma_f32_16x16x32_bf16(af[i], bfr[j], acc[i][j], 0, 0, 0);
  }

  if constexpr (EPI == 1) {
    unsigned short* C = (unsigned short*)Cpv + (long long)bz * sC;
#pragma unroll
    for (int i = 0; i < 4; ++i) {
#pragma unroll
      for (int r = 0; r < 4; ++r) {
        int m = m0 + wm + i * 16 + q * 4 + r;
        float ps = 0.f;
#pragma unroll
        for (int j = 0; j < 4; ++j) {
          int n = n0 + wn + j * 16 + r16;
          float v = __expf(acc[i][j][r] * escale);
          ps += v;
          C[(size_t)m * ldc + n] = f2b(v);
        }
        // reduce over the 16 lanes sharing this row
#pragma unroll
        for (int msk = 1; msk < 16; msk <<= 1) ps += __shfl_xor(ps, msk, 64);
        if (r16 == 0) atomicAdd(&sums[(long long)bz * sstride + m], ps);
      }
    }
  } else {
    float* C = (float*)Cpv + (long long)bz * sC;
    const float* sb = sums + (long long)bz * sstride;
#pragma unroll
    for (int i = 0; i < 4; ++i) {
#pragma unroll
      for (int r = 0; r < 4; ++r) {
        int m = m0 + wm + i * 16 + q * 4 + r;
        float sc = 1.0f / sb[m];
#pragma unroll
        for (int j = 0; j < 4; ++j) {
          int n = n0 + wn + j * 16 + r16;
          C[(size_t)m * ldc + n] = acc[i][j][r] * sc;
        }
      }
    }
  }
}

// ---------- launch ----------
extern "C" void kernel_launch(void* const* d_in, const int* in_sizes, int n_in,
                              void* d_out, int out_size, void* d_ws, size_t ws_size,
                              hipStream_t stream) {
  (void)in_sizes; (void)n_in; (void)out_size; (void)ws_size;
  const float* H  = (const float*)d_in[0];   // [16][2048][1280]
  const float* G  = (const float*)d_in[1];   // [16][512][768]
  const float* Wq = (const float*)d_in[2];   // [256][768]
  const float* Wk = (const float*)d_in[3];   // [256][1280]
  float* Z = (float*)d_out;                  // [16][512][1280]

  constexpr int B = 16, L = 2048, Dh = 1280, T = 512, Dg = 768, P = 256;

  char* ws = (char*)d_ws;
  size_t off = 0;
  auto alloc = [&](size_t bytes) { void* p = ws + off; off += (bytes + 255) & ~(size_t)255; return p; };
  unsigned short* Wqbf = (unsigned short*)alloc((size_t)P * Dg * 2);
  unsigned short* Wkbf = (unsigned short*)alloc((size_t)P * Dh * 2);
  unsigned short* Qbf  = (unsigned short*)alloc((size_t)B * T * P * 2);    // 4 MB
  unsigned short* Kbf  = (unsigned short*)alloc((size_t)B * L * P * 2);    // 16 MB
  unsigned short* HT   = (unsigned short*)alloc((size_t)B * Dh * L * 2);   // 80 MB
  unsigned short* E    = (unsigned short*)alloc((size_t)B * T * L * 2);    // 32 MB
  float*          sums = (float*)alloc((size_t)B * T * 4);
  // total ~132 MB of ws

  // weights convert + sums zero-init (one small kernel)
  {
    int na4 = P * Dg / 4, nb4 = P * Dh / 4, nz = B * T;
    cvtw_kernel<<<(na4 + nb4 + nz + 255) / 256, 256, 0, stream>>>(
        Wq, Wqbf, na4, Wk, Wkbf, nb4, sums, nz);
  }

  // Q = G(f32) * Wqbf^T : [8192][256], G fetched once
  proj_gemm<0><<<B * T / 64, 256, 0, stream>>>(G, Wqbf, Qbf, nullptr, Dg, Dg);
  // K = H(f32) * Wkbf^T : [32768][256], H fetched once; also emits HT bf16
  proj_gemm<1><<<B * L / 64, 256, 0, stream>>>(H, Wkbf, Kbf, HT, Dh, Dh);

  // E = exp(scale * Qb * Kb^T) + row sums : per b [512][2048], 64 tiles/batch
  gemm_nt<1><<<B * (T / 128) * (L / 128), 256, 0, stream>>>(
      Qbf, Kbf, E, sums, P, P, P, L,
      (long long)T * P, (long long)L * P, (long long)T * L, T,
      0.0625f, L / 128, (T / 128) * (L / 128));

  // Z = diag(1/sums) * Eb * HTb^T : per b [512][1280] f32, 40 tiles/batch
  gemm_nt<2><<<B * (T / 128) * (Dh / 128), 256, 0, stream>>>(
      E, HT, Z, sums, L, L, L, Dh,
      (long long)T * L, (long long)Dh * L, (long long)T * Dh, T,
      0.f, Dh / 128, (T / 128) * (Dh / 128));
}